// Round 7
// baseline (400.061 us; speedup 1.0000x reference)
//
#include <hip/hip_runtime.h>
#include <stdint.h>

// x [B=32, C=512, H=32, W=32] fp32, 32 groups, S = H*W = 1024. All I/O fp32.
// Internal tensors bf16: xt[b][s][c], qkt[b][s][1024] (q|k fused), v[b][d][s],
// Sc[b][s][t] bf16 (RAW scaled scores; softmax fused), o_t[b][s][c].
// All GEMMs NT (Out[m][n] = sum_k A[m][k]B[n][k]) on mfma_f32_16x16x32_bf16:
//   A-frag: A[m=lane&15][k=quad*8+j]  B-frag: B[n=lane&15][k=quad*8+j]
//   C/D:    col=lane&15, row=quad*4+reg
// R7: bijective XCD-aware block swizzle (T1): scores FETCH 166->49MB.
// R12: 2 barriers/tile + counted vmcnt + counted lgkm (overlap LDS drain
//   under MFMA). GEMM plateau ~650-730 TF; schedule micro-tuning exhausted.
// R13: FUSED SOFTMAX (work deletion, not scheduling):
//   - scores (EPI 2) epilogue computes per-(row, 64col-slice) partials
//     (max, sum exp) via 16-lane shfl_xor butterfly -> statsA[b][16][1024].
//   - softmax kernel DELETED (was 2 dispatches + 128 MB HBM round trip).
//   - PV (EPI 5) prologue combines 16 partials/row (online-softmax rule),
//     caches (M, 1/S) in LDS + regs; K-loop applies p=exp(s-M)*invS on
//     A-frags between lgkm-wait and MFMA. bf16 rounding point identical to
//     the old softmax kernel -> absmax unchanged.
#define Bsz 32
#define Cch 512
#define Ssp 1024
#define Grp 32
#define CPG 16

typedef unsigned short u16;
typedef __attribute__((ext_vector_type(8))) short bf16x8;
typedef __attribute__((ext_vector_type(4))) float f32x4;

__device__ __forceinline__ float bf2f(u16 u) {
  union { float f; uint32_t i; } w; w.i = ((uint32_t)u) << 16; return w.f;
}
__device__ __forceinline__ u16 f2bf(float f) {
  union { float f; uint32_t i; } w; w.f = f;
  uint32_t r = w.i + 0x7fffu + ((w.i >> 16) & 1u);  // RNE
  return (u16)(r >> 16);
}

__device__ __forceinline__ void gload_lds16(const u16* g, u16* l) {
  __builtin_amdgcn_global_load_lds(
      (const __attribute__((address_space(1))) uint32_t*)g,
      (__attribute__((address_space(3))) uint32_t*)l, 16, 0, 0);
}

// P = exp(s - M) * invS applied to one bf16x8 score fragment (one row).
__device__ __forceinline__ bf16x8 pxf(bf16x8 s, float M, float I) {
  bf16x8 r;
#pragma unroll
  for (int j = 0; j < 8; ++j) {
    float v = bf2f((u16)s[j]);
    r[j] = (short)f2bf(__expf(v - M) * I);
  }
  return r;
}

// ---------------- GN stats: one block per (b,g) -> per-channel affine (A,B) ----
__global__ __launch_bounds__(256) void gnstats_kernel(
    const float* __restrict__ x, const float* __restrict__ scale,
    const float* __restrict__ bias, float2* __restrict__ stats) {
  int b = blockIdx.x >> 5;
  int g = blockIdx.x & 31;
  size_t base = ((size_t)b * Cch + (size_t)g * CPG) * Ssp;
  const float4* xv = (const float4*)(x + base);

  float sum = 0.f, sumsq = 0.f;
#pragma unroll
  for (int it = 0; it < 16; ++it) {
    float4 v = xv[threadIdx.x + 256 * it];
    sum += (v.x + v.y) + (v.z + v.w);
    sumsq += (v.x * v.x + v.y * v.y) + (v.z * v.z + v.w * v.w);
  }
#pragma unroll
  for (int off = 32; off > 0; off >>= 1) {
    sum += __shfl_xor(sum, off);
    sumsq += __shfl_xor(sumsq, off);
  }
  __shared__ float sm[8];
  int wid = threadIdx.x >> 6;
  if ((threadIdx.x & 63) == 0) { sm[wid] = sum; sm[4 + wid] = sumsq; }
  __syncthreads();
  sum = sm[0] + sm[1] + sm[2] + sm[3];
  sumsq = sm[4] + sm[5] + sm[6] + sm[7];
  float mean = sum * (1.f / 16384.f);
  float var = sumsq * (1.f / 16384.f) - mean * mean;
  float rstd = rsqrtf(var + 1e-6f);
  if (threadIdx.x < CPG) {
    int c = g * CPG + threadIdx.x;
    float sc = scale[c] * rstd;
    stats[(size_t)b * Cch + c] = make_float2(sc, bias[c] - mean * sc);
  }
}

// ---------------- x[b][c][s] fp32 -> xt[b][s][c] bf16 with GN affine ----------
__global__ __launch_bounds__(256) void xpose_gn(
    const float* __restrict__ x, const float2* __restrict__ stats,
    u16* __restrict__ xt) {
  __shared__ float T[64][65];
  int b = blockIdx.z;
  int s0 = blockIdx.x * 64, c0 = blockIdx.y * 64;
  int t = threadIdx.x;
  {
    int tx = t & 15, ty = t >> 4;
    const float* xb = x + ((size_t)b * Cch + c0) * Ssp + s0;
#pragma unroll
    for (int i = 0; i < 4; ++i) {
      int c = ty + 16 * i;
      float2 af = stats[(size_t)b * Cch + c0 + c];
      float4 v = *(const float4*)&xb[(size_t)c * Ssp + tx * 4];
      T[c][tx * 4 + 0] = v.x * af.x + af.y;
      T[c][tx * 4 + 1] = v.y * af.x + af.y;
      T[c][tx * 4 + 2] = v.z * af.x + af.y;
      T[c][tx * 4 + 3] = v.w * af.x + af.y;
    }
  }
  __syncthreads();
  {
    int cx = t & 7, sy = t >> 3;
    u16* ob = xt + ((size_t)b * Ssp + s0) * Cch + c0;
#pragma unroll
    for (int i = 0; i < 2; ++i) {
      int s = sy + 32 * i;
      union { u16 h[8]; uint4 v4; } pk;
#pragma unroll
      for (int j = 0; j < 8; ++j) pk.h[j] = f2bf(T[cx * 8 + j][s]);
      *(uint4*)&ob[(size_t)s * Cch + cx * 8] = pk.v4;
    }
  }
}

// ---------------- W[c][d] fp32 (512x512) -> Wt[d][c] bf16, 4 weights ----------
__global__ __launch_bounds__(256) void wxpose(
    const float* __restrict__ w0, const float* __restrict__ w1,
    const float* __restrict__ w2, const float* __restrict__ w3,
    u16* __restrict__ dst) {
  const float* W = blockIdx.z == 0 ? w0 : blockIdx.z == 1 ? w1
                   : blockIdx.z == 2 ? w2 : w3;
  u16* D = dst + (size_t)blockIdx.z * Cch * Cch;
  __shared__ float T[64][65];
  int d0 = blockIdx.x * 64, c0 = blockIdx.y * 64;
  int t = threadIdx.x;
  {
    int tx = t & 15, ty = t >> 4;
#pragma unroll
    for (int i = 0; i < 4; ++i) {
      int c = ty + 16 * i;
      float4 v = *(const float4*)&W[(size_t)(c0 + c) * Cch + d0 + tx * 4];
      T[c][tx * 4 + 0] = v.x; T[c][tx * 4 + 1] = v.y;
      T[c][tx * 4 + 2] = v.z; T[c][tx * 4 + 3] = v.w;
    }
  }
  __syncthreads();
  {
    int cx = t & 7, dy = t >> 3;
#pragma unroll
    for (int i = 0; i < 2; ++i) {
      int d = dy + 32 * i;
      union { u16 h[8]; uint4 v4; } pk;
#pragma unroll
      for (int j = 0; j < 8; ++j) pk.h[j] = f2bf(T[cx * 8 + j][d]);
      *(uint4*)&D[(size_t)(d0 + d) * Cch + c0 + cx * 8] = pk.v4;
    }
  }
}

// ---- R12/R13: 256x256 BK=64 8-wave NT GEMM, 2 barriers/tile, counted waits ---
// 8 waves 2(M)x4(N); per-wave 128x64 = 8 m-frags x 4 n-frags (32 f32x4 acc).
// LDS per operand: 2 bufs x 32KB; unit = proven row-pair-XOR layout.
// Per tile: two khalf superphases: {vm-wait(4) -> BAR -> 12 ds_reads ->
// lgkm(4) -> [EPI5: exp-transform a] -> MFMA m0-3 -> STG next khalf ->
// lgkm(0) -> [EPI5: exp a2] -> MFMA m4-7}. Never vmcnt(0) in steady state.
// EPI 0: bf16 + bias(n<512?bias:b2)      (fused q|k proj)
// EPI 1: bf16 + bias[m]                  (v proj -> v[d][s])
// EPI 2: bf16 * C^-0.5 + softmax partials (max, sumexp) -> statsA (bias ptr)
// EPI 4: f32 + bias[m] + resid           (final -> out[d][s])
// EPI 5: A-frags get p=exp(s-M)*invS (fused softmax PV); bf16 out
template <int EPI>
__global__ __launch_bounds__(512, 2) void mfma_ntf(
    const u16* __restrict__ A, size_t sAb, int lda,
    const u16* __restrict__ B, size_t sBb, int ldb,
    void* __restrict__ Out, size_t sOb, int ldo,
    const float* __restrict__ bias,
    const float* __restrict__ bias2_or_resid, size_t sRb, int K) {
  __shared__ u16 As[2 * 16384];  // 64 KB
  __shared__ u16 Bs[2 * 16384];  // 64 KB
  __shared__ float2 smrow[256];  // EPI5: per-row (M, 1/S)

  // bijective XCD-aware swizzle (R7)
  const int nx = gridDim.x, ny = gridDim.y;
  const int pb = nx * ny;
  const int nwg = pb * gridDim.z;
  const int flat = (blockIdx.z * ny + blockIdx.y) * nx + blockIdx.x;
  const int qq = nwg >> 3, rr = nwg & 7;
  const int xcd = flat & 7, lid = flat >> 3;
  const int nf2 = (xcd < rr ? xcd * (qq + 1) : rr * (qq + 1) + (xcd - rr) * qq) + lid;
  const int b = nf2 / pb;
  const int rem = nf2 - b * pb;
  const int m0 = (rem / nx) * 256, n0 = (rem % nx) * 256;

  const int tid = threadIdx.x;
  const int lane = tid & 63, wave = tid >> 6;  // 0..7
  const int wm = wave >> 2, wn = wave & 3;     // 2(M) x 4(N)
  const int quad = lane >> 4, l16 = lane & 15;

  // staging decode (proven): phys chunk p = lane&7 of pair q' = lane>>3 within
  // a 16-row unit; logical c = p ^ q' -> row 2q' + (c>>2), k-off (c&3)*8.
  const int sp = lane & 7, sq = lane >> 3;
  const int scl = sp ^ sq;
  const int srow = 2 * sq + (scl >> 2);
  const int scol = (scl & 3) * 8;

  // fragment-read per-lane offset within a 512-elem unit
  const int vbase =
      ((l16 >> 1) << 6) + ((((l16 & 1) << 2) | quad) ^ (l16 >> 1)) * 8;

  const u16* Ab = A + (size_t)b * sAb + (size_t)m0 * lda;
  const u16* Bb = B + (size_t)b * sBb + (size_t)n0 * ldb;

  // ---- EPI5 prologue: combine 16 softmax partials/row -> (M, invS) ----
  float Mr[8], Ir[8];
  if constexpr (EPI == 5) {
    const float2* statsA = (const float2*)bias;
    if (tid < 256) {
      float2 pp[16];
#pragma unroll
      for (int j = 0; j < 16; ++j)
        pp[j] = statsA[((size_t)b * 16 + j) * 1024 + m0 + tid];
      float M = pp[0].x;
#pragma unroll
      for (int j = 1; j < 16; ++j) M = fmaxf(M, pp[j].x);
      float S = 0.f;
#pragma unroll
      for (int j = 0; j < 16; ++j) S += __expf(pp[j].x - M) * pp[j].y;
      smrow[tid] = make_float2(M, 1.f / S);
    }
    __syncthreads();
#pragma unroll
    for (int mf = 0; mf < 8; ++mf) {
      float2 mi = smrow[wm * 128 + mf * 16 + l16];  // A-frag row = l16
      Mr[mf] = mi.x;
      Ir[mf] = mi.y;
    }
  }

  f32x4 acc[8][4] = {};

  // stage both segment-groups (su=wave, su=8+wave) of khalf kh for tile kt1
#define STGH(kh, kt1, nbuf)                                                    \
  {                                                                            \
    _Pragma("unroll") for (int i_ = 0; i_ < 2; ++i_) {                         \
      const int su_ = i_ * 8 + wave;                                           \
      gload_lds16(Ab + (size_t)(su_ * 16 + srow) * lda + (kt1) * 64 +          \
                      (kh) * 32 + scol,                                        \
                  As + (nbuf) * 16384 + (kh) * 8192 + su_ * 512);              \
      gload_lds16(Bb + (size_t)(su_ * 16 + srow) * ldb + (kt1) * 64 +          \
                      (kh) * 32 + scol,                                        \
                  Bs + (nbuf) * 16384 + (kh) * 8192 + su_ * 512);              \
    }                                                                          \
  }

  // fragment loads from buf cur
#define LDA(mf, kk) \
  (*(const bf16x8*)&As[cur * 16384 + (kk) * 8192 + (wm * 8 + (mf)) * 512 + vbase])
#define LDB(nf, kk) \
  (*(const bf16x8*)&Bs[cur * 16384 + (kk) * 8192 + (wn * 4 + (nf)) * 512 + vbase])

#define BAR asm volatile("s_barrier" ::: "memory")
#define WAIT_VM(n) asm volatile("s_waitcnt vmcnt(" #n ")" ::: "memory")
#define WAIT_LGKM(n)                                      \
  asm volatile("s_waitcnt lgkmcnt(" #n ")" ::: "memory"); \
  __builtin_amdgcn_sched_barrier(0)
#define SB0 __builtin_amdgcn_sched_barrier(0)

  // prologue: stage tile 0 into buf 0, kh0 group first (vm-count ordering)
  STGH(0, 0, 0)
  STGH(1, 0, 0)

  const int nk = K >> 6;
  bf16x8 bf[4], a[4], a2[4];
  for (int kt = 0; kt < nk; ++kt) {
    const int cur = kt & 1;
    const int nbuf = cur ^ 1;
    const bool nxt = (kt + 1 < nk);

    // ================= khalf 0 =================
    WAIT_VM(4);  // drain kh0(t) (oldest 4); kh1(t) stays in flight
    BAR;         // all waves' kh0 loads landed -> buf[cur].kh0 valid
#pragma unroll
    for (int i = 0; i < 4; ++i) bf[i] = LDB(i, 0);
#pragma unroll
    for (int i = 0; i < 4; ++i) a[i] = LDA(i, 0);
    SB0;  // pin group order: these 8 are the oldest lgkm ops
#pragma unroll
    for (int i = 0; i < 4; ++i) a2[i] = LDA(4 + i, 0);
    WAIT_LGKM(4);  // first 8 (bf, a) done; a2's 4 drain under MFMA below
    if constexpr (EPI == 5) {
#pragma unroll
      for (int i = 0; i < 4; ++i) a[i] = pxf(a[i], Mr[i], Ir[i]);
    }
    __builtin_amdgcn_s_setprio(1);
#pragma unroll
    for (int mf = 0; mf < 4; ++mf)
#pragma unroll
      for (int nf = 0; nf < 4; ++nf)
        acc[mf][nf] = __builtin_amdgcn_mfma_f32_16x16x32_bf16(
            a[mf], bf[nf], acc[mf][nf], 0, 0, 0);
    __builtin_amdgcn_s_setprio(0);
    if (nxt) STGH(0, kt + 1, nbuf)  // 4 vmem: kh0 of t+1
    WAIT_LGKM(0);                   // a2 ready
    if constexpr (EPI == 5) {
#pragma unroll
      for (int i = 0; i < 4; ++i) a2[i] = pxf(a2[i], Mr[4 + i], Ir[4 + i]);
    }
    __builtin_amdgcn_s_setprio(1);
#pragma unroll
    for (int mf = 0; mf < 4; ++mf)
#pragma unroll
      for (int nf = 0; nf < 4; ++nf)
        acc[4 + mf][nf] = __builtin_amdgcn_mfma_f32_16x16x32_bf16(
            a2[mf], bf[nf], acc[4 + mf][nf], 0, 0, 0);
    __builtin_amdgcn_s_setprio(0);

    // ================= khalf 1 =================
    if (nxt) { WAIT_VM(4); } else { WAIT_VM(0); }  // drain kh1(t)
    BAR;  // all waves' kh1 loads landed -> buf[cur].kh1 valid
#pragma unroll
    for (int i = 0; i < 4; ++i) bf[i] = LDB(i, 1);
#pragma unroll
    for (int i = 0; i < 4; ++i) a[i] = LDA(i, 1);
    SB0;
#pragma unroll
    for (int i = 0; i < 4; ++i) a2[i] = LDA(4 + i, 1);
    WAIT_LGKM(4);
    if constexpr (EPI == 5) {
#pragma unroll
      for (int i = 0; i < 4; ++i) a[i] = pxf(a[i], Mr[i], Ir[i]);
    }
    __builtin_amdgcn_s_setprio(1);
#pragma unroll
    for (int mf = 0; mf < 4; ++mf)
#pragma unroll
      for (int nf = 0; nf < 4; ++nf)
        acc[mf][nf] = __builtin_amdgcn_mfma_f32_16x16x32_bf16(
            a[mf], bf[nf], acc[mf][nf], 0, 0, 0);
    __builtin_amdgcn_s_setprio(0);
    if (nxt) STGH(1, kt + 1, nbuf)  // 4 vmem: kh1 of t+1
    WAIT_LGKM(0);
    if constexpr (EPI == 5) {
#pragma unroll
      for (int i = 0; i < 4; ++i) a2[i] = pxf(a2[i], Mr[4 + i], Ir[4 + i]);
    }
    __builtin_amdgcn_s_setprio(1);
#pragma unroll
    for (int mf = 0; mf < 4; ++mf)
#pragma unroll
      for (int nf = 0; nf < 4; ++nf)
        acc[4 + mf][nf] = __builtin_amdgcn_mfma_f32_16x16x32_bf16(
            a2[mf], bf[nf], acc[4 + mf][nf], 0, 0, 0);
    __builtin_amdgcn_s_setprio(0);
  }
#undef STGH
#undef LDA
#undef LDB

  const float SCALE = 0.044194173824159216f;  // 512^-0.5
#pragma unroll
  for (int mf = 0; mf < 8; ++mf) {
#pragma unroll
    for (int nf = 0; nf < 4; ++nf) {
      int n = n0 + wn * 64 + nf * 16 + l16;
      float bn = 0.f;
      if constexpr (EPI == 0)
        bn = (n < 512) ? bias[n] : bias2_or_resid[n - 512];
#pragma unroll
      for (int reg = 0; reg < 4; ++reg) {
        int m = m0 + wm * 128 + mf * 16 + quad * 4 + reg;
        float v = acc[mf][nf][reg];
        size_t idx = (size_t)b * sOb + (size_t)m * ldo + n;
        if constexpr (EPI == 0) {
          ((u16*)Out)[idx] = f2bf(v + bn);
        } else if constexpr (EPI == 1) {
          ((u16*)Out)[idx] = f2bf(v + bias[m]);
        } else if constexpr (EPI == 2) {
          ((u16*)Out)[idx] = f2bf(v * SCALE);
        } else if constexpr (EPI == 5) {
          ((u16*)Out)[idx] = f2bf(v);
        } else {
          ((float*)Out)[idx] =
              v + bias[m] + bias2_or_resid[(size_t)b * sRb + (size_t)m * ldo + n];
        }
      }
    }
  }

  // ---- EPI2: per-row softmax partials over this block's 256-col slice ----
  // Row r (of 256): values live in lanes l16 (cols) x regs nf; reduce via
  // 16-lane shfl_xor butterfly. Partial slice id = (n0/256)*4 + wn.
  if constexpr (EPI == 2) {
    float2* statsA = (float2*)bias;  // [b][16][1024] (chunk-local b)
    const int slice = ((n0 >> 8) << 2) + wn;
#pragma unroll
    for (int mf = 0; mf < 8; ++mf) {
#pragma unroll
      for (int reg = 0; reg < 4; ++reg) {
        float lm = -1e30f;
#pragma unroll
        for (int nf = 0; nf < 4; ++nf)
          lm = fmaxf(lm, bf2f(f2bf(acc[mf][nf][reg] * SCALE)));
#pragma unroll
        for (int off = 8; off > 0; off >>= 1)
          lm = fmaxf(lm, __shfl_xor(lm, off));
        float ls = 0.f;
#pragma unroll
        for (int nf = 0; nf < 4; ++nf)
          ls += __expf(bf2f(f2bf(acc[mf][nf][reg] * SCALE)) - lm);
#pragma unroll
        for (int off = 8; off > 0; off >>= 1) ls += __shfl_xor(ls, off);
        if (l16 == 0) {
          int row = m0 + wm * 128 + mf * 16 + quad * 4 + reg;
          statsA[((size_t)b * 16 + slice) * 1024 + row] = make_float2(lm, ls);
        }
      }
    }
  }
}

extern "C" void kernel_launch(void* const* d_in, const int* in_sizes, int n_in,
                              void* d_out, int out_size, void* d_ws, size_t ws_size,
                              hipStream_t stream) {
  (void)in_sizes; (void)n_in; (void)out_size;
  const float* x   = (const float*)d_in[0];
  const float* gns = (const float*)d_in[1];
  const float* gnb = (const float*)d_in[2];
  const float* Wq  = (const float*)d_in[3];
  const float* bq  = (const float*)d_in[4];
  const float* Wk  = (const float*)d_in[5];
  const float* bk  = (const float*)d_in[6];
  const float* Wv  = (const float*)d_in[7];
  const float* bv  = (const float*)d_in[8];
  const float* Wt  = (const float*)d_in[9];
  const float* bt  = (const float*)d_in[10];
  float* out = (float*)d_out;
  char* ws = (char*)d_ws;

  // Workspace:
  //   qkt @ 0MB   (64MB bf16 [b][s][1024], q|k fused) -> o_t aliases its start
  //   v   @ 64MB  (32MB bf16 [b][d][s])
  //   W_t @ 96MB  (4 x 0.5MB bf16 [d][c])
  //   stats @98MB (256KB float2 GN; dead after xpose -> statsA may reuse)
  //   xt  @ 99MB  (32MB bf16 [b][s][c]) -> dead after projections
  //   Sc  @ 99MB  (NB*2MB bf16 raw scores, overlays xt)
  //   statsA: softmax partials [NB][16][1024] float2 (NB*128KB):
  //     NB=16 -> @131MB (needs ws>=134MB); NB=8 -> @98MB (reuses GN region)
  const size_t QKSZ = (size_t)Bsz * Ssp * 1024 * 2;  // 64 MB
  u16* qkt = (u16*)ws;
  u16* vv  = (u16*)(ws + QKSZ);
  u16* Wts = (u16*)(ws + (96ull << 20));
  float2* stats = (float2*)(ws + (98ull << 20));
  u16* xt  = (u16*)(ws + (99ull << 20));
  u16* Sc  = xt;
  u16* ot  = qkt;

  int NB;
  float2* statsA;
  if (ws_size >= (167ull << 20)) {
    NB = 32; statsA = (float2*)(ws + (163ull << 20));
  } else if (ws_size >= (134ull << 20)) {
    NB = 16; statsA = (float2*)(ws + (131ull << 20));
  } else {
    NB = 8; statsA = (float2*)(ws + (98ull << 20));  // GN stats region (dead)
  }

  const size_t WSZ = (size_t)Cch * Cch;
  u16* Wvt = Wts + 2 * WSZ;
  u16* Wtt = Wts + 3 * WSZ;

  const size_t sSC  = (size_t)Ssp * Cch;   // xt / o_t per-batch elems
  const size_t sQK  = (size_t)Ssp * 1024;  // qkt per-batch elems
  const size_t sCS  = (size_t)Cch * Ssp;   // v / x / out per-batch elems
  const size_t sScB = (size_t)Ssp * Ssp;   // score per-batch elems (bf16)
  dim3 blk(256);
  dim3 blk8(512);

  gnstats_kernel<<<dim3(Bsz * Grp), blk, 0, stream>>>(x, gns, gnb, stats);
  xpose_gn<<<dim3(Ssp / 64, Cch / 64, Bsz), blk, 0, stream>>>(x, stats, xt);
  wxpose<<<dim3(8, 8, 4), blk, 0, stream>>>(Wq, Wk, Wv, Wt, Wts);

  // Grids: x = N/256, y = M/256, z = batch
  // fused q|k: m=s(1024), n=dq|dk(1024), k=c(512): A=xt, B=Wq_t|Wk_t
  mfma_ntf<0><<<dim3(4, 4, Bsz), blk8, 0, stream>>>(
      xt, sSC, Cch, Wts, 0, Cch, qkt, sQK, 1024, bq, bk, 0, Cch);
  // v: m=d(512), n=s(1024), k=c(512): A=Wv_t, B=xt -> v[d][s] + bias[m]
  mfma_ntf<1><<<dim3(4, 2, Bsz), blk8, 0, stream>>>(
      Wvt, 0, Cch, xt, sSC, Cch, vv, sCS, Ssp, bv, nullptr, 0, Cch);

  for (int b0 = 0; b0 < Bsz; b0 += NB) {
    int nb = (b0 + NB <= Bsz) ? NB : (Bsz - b0);
    // scores: m=s, n=s', k=d: A=q, B=k -> Sc bf16 raw *C^-0.5 + partials
    mfma_ntf<2><<<dim3(4, 4, nb), blk8, 0, stream>>>(
        qkt + b0 * sQK, sQK, 1024, qkt + b0 * sQK + 512, sQK, 1024,
        Sc, sScB, Ssp, (const float*)statsA, nullptr, 0, Cch);
    // PV fused softmax: m=s(1024), n=c(512), k=t(1024): A=exp(Sc), B=v
    mfma_ntf<5><<<dim3(2, 4, nb), blk8, 0, stream>>>(
        Sc, sScB, Ssp, vv + b0 * sCS, sCS, Ssp,
        ot + b0 * sSC, sSC, Cch, (const float*)statsA, nullptr, 0, Ssp);
  }

  // final: m=d(512), n=s(1024), k=c(512): A=Wt_t, B=o_t -> fp32 +bias[m]+x
  mfma_ntf<4><<<dim3(4, 2, Bsz), blk8, 0, stream>>>(
      Wtt, 0, Cch, ot, sSC, Cch, out, sCS, Ssp, bt, x, sCS, Cch);
}